// Round 3
// baseline (396.993 us; speedup 1.0000x reference)
//
#include <hip/hip_runtime.h>

// LiftSplatShoot dims
#define B_   8
#define N_   6
#define D_   41
#define FH_  8
#define FW_  22
#define C_   64
#define NPRIME (B_*N_*D_*FH_*FW_)   // 346368
#define NX0  200
#define NX1  200
#define OUTSZ (B_*C_*NX0*NX1)       // 20,480,000 floats

// Replicates numpy float32 np.linalg.inv: LAPACK sgetrf (getf2/recursive getrf2 —
// identical per-element op sequence for 3x3) + sgetri (strti2 + unblocked column
// sweep + column interchanges). Column-major internally, reciprocal-scale pivots,
// non-fused mul/add (contract off).
__device__ void lapack_inv3_f32(const float Ain[9] /*row-major*/, float Aout[9] /*row-major*/) {
    #pragma clang fp contract(off)
    float a[9]; // column-major a[c*3+r]
    for (int r = 0; r < 3; ++r)
        for (int c = 0; c < 3; ++c)
            a[c*3 + r] = Ain[r*3 + c];
    int ipiv[3];
    // ---- sgetf2 ----
    for (int j = 0; j < 3; ++j) {
        int p = j;
        float amax = fabsf(a[j*3 + j]);
        for (int i = j + 1; i < 3; ++i) {         // isamax: first strict max
            float v = fabsf(a[j*3 + i]);
            if (v > amax) { amax = v; p = i; }
        }
        ipiv[j] = p;
        if (p != j)
            for (int c = 0; c < 3; ++c) { float t = a[c*3+j]; a[c*3+j] = a[c*3+p]; a[c*3+p] = t; }
        float d = 1.0f / a[j*3 + j];              // |pivot| >= sfmin path: scale by reciprocal
        for (int i = j + 1; i < 3; ++i) a[j*3 + i] = a[j*3 + i] * d;
        // sger: for each column jj: temp = -U(j,jj); A(ii,jj) += L(ii,j)*temp
        for (int jj = j + 1; jj < 3; ++jj) {
            float temp = -a[jj*3 + j];
            for (int ii = j + 1; ii < 3; ++ii)
                a[jj*3 + ii] = a[jj*3 + ii] + a[j*3 + ii] * temp;
        }
    }
    // ---- strti2 (invert U in place) ----
    for (int j = 0; j < 3; ++j) {
        float ajj_inv = 1.0f / a[j*3 + j];
        a[j*3 + j] = ajj_inv;
        float AJJ = -ajj_inv;
        // strmv 'U','N','N': x = U(0:j,0:j) * x, x = A(0:j, j)
        for (int jj = 0; jj < j; ++jj) {
            float temp = a[j*3 + jj];
            for (int i = 0; i < jj; ++i)
                a[j*3 + i] = a[j*3 + i] + temp * a[jj*3 + i];
            a[j*3 + jj] = a[j*3 + jj] * a[jj*3 + jj];
        }
        for (int i = 0; i < j; ++i) a[j*3 + i] = a[j*3 + i] * AJJ;   // sscal
    }
    // ---- sgetri unblocked sweep ----
    float work[3];
    for (int j = 2; j >= 0; --j) {
        for (int i = j + 1; i < 3; ++i) { work[i] = a[j*3 + i]; a[j*3 + i] = 0.0f; }
        // sgemv 'N', alpha=-1, beta=1: y = y - A(:, j+1:)*work(j+1:)
        for (int jj = j + 1; jj < 3; ++jj) {
            float temp = -work[jj];
            for (int i = 0; i < 3; ++i)
                a[j*3 + i] = a[j*3 + i] + temp * a[jj*3 + i];
        }
    }
    // ---- column interchanges (reverse) ----
    for (int j = 2; j >= 0; --j) {
        int p = ipiv[j];
        if (p != j)
            for (int i = 0; i < 3; ++i) { float t = a[j*3+i]; a[j*3+i] = a[p*3+i]; a[p*3+i] = t; }
    }
    for (int r = 0; r < 3; ++r)
        for (int c = 0; c < 3; ++c)
            Aout[r*3 + c] = a[c*3 + r];
}

// Zero the output grid (harness poisons d_out with 0xAA before every launch).
__global__ void zero_kernel(float4* __restrict__ out, int n4) {
    int i = blockIdx.x * blockDim.x + threadIdx.x;
    if (i < n4) out[i] = make_float4(0.f, 0.f, 0.f, 0.f);
}

// Per-(b,n): inv(post_rots), combine = rots @ inv(intrins), all float32,
// numpy op order, no FMA contraction.
// mats layout per bn (24 floats): [invPR 0..8 | combine 9..17 | post_trans 18..20 | trans 21..23]
__global__ void prep_kernel(const float* __restrict__ rots,
                            const float* __restrict__ trans,
                            const float* __restrict__ intrins,
                            const float* __restrict__ post_rots,
                            const float* __restrict__ post_trans,
                            float* __restrict__ mats) {
    #pragma clang fp contract(off)
    int t = threadIdx.x;
    if (t >= B_ * N_) return;
    float pr[9], ipr[9], K[9], iK[9];
    for (int i = 0; i < 9; ++i) { pr[i] = post_rots[t*9 + i]; K[i] = intrins[t*9 + i]; }
    lapack_inv3_f32(pr, ipr);
    lapack_inv3_f32(K, iK);
    float* m = mats + t * 24;
    for (int i = 0; i < 9; ++i) m[i] = ipr[i];
    // combine = rots @ invK, f32, j ascending: ((r0*k0 + r1*k1) + r2*k2)
    for (int i = 0; i < 3; ++i)
        for (int k = 0; k < 3; ++k) {
            float s = rots[t*9 + i*3 + 0] * iK[0*3 + k];
            s = s + rots[t*9 + i*3 + 1] * iK[1*3 + k];
            s = s + rots[t*9 + i*3 + 2] * iK[2*3 + k];
            m[9 + i*3 + k] = s;
        }
    for (int i = 0; i < 3; ++i) {
        m[18 + i] = post_trans[t*3 + i];
        m[21 + i] = trans[t*3 + i];
    }
}

// One thread per point: float32 geometry chain (numpy-faithful) -> voxel bin
// -> out base offset (or -1).
__global__ void geom_kernel(const float* __restrict__ mats, int* __restrict__ vox) {
    #pragma clang fp contract(off)
    int p = blockIdx.x * blockDim.x + threadIdx.x;
    if (p >= NPRIME) return;
    int w  = p % FW_;
    int h  = (p / FW_) % FH_;
    int d  = (p / (FW_ * FH_)) % D_;
    int bn = p / (FW_ * FH_ * D_);
    int b  = bn / N_;

    const float* m = mats + bn * 24;

    // np.linspace(..., dtype=float32): computed fp64, rounded, endpoint forced.
    float xs = (w == FW_ - 1) ? 351.0f : (float)((double)w * (351.0 / 21.0));
    float ys = (h == FH_ - 1) ? 127.0f : (float)((double)h * (127.0 / 7.0));
    float ds = 4.0f + (float)d;               // arange(4,45) exact

    // pts = frustum - post_trans (f32)
    float px = xs - m[18], py = ys - m[19], pz = ds - m[20];
    // einsum inv_pr @ pts, j ascending, f32, no fma
    float qx = m[0]*px;  qx = qx + m[1]*py;  qx = qx + m[2]*pz;
    float qy = m[3]*px;  qy = qy + m[4]*py;  qy = qy + m[5]*pz;
    float qz = m[6]*px;  qz = qz + m[7]*py;  qz = qz + m[8]*pz;

    // unproject (u*d, v*d, d) f32
    float ux = qx * qz, uy = qy * qz, uz = qz;

    // geom = combine @ u + trans, j ascending, f32, no fma
    float gx = m[9]*ux;   gx = gx + m[10]*uy;  gx = gx + m[11]*uz;  gx = gx + m[21];
    float gy = m[12]*ux;  gy = gy + m[13]*uy;  gy = gy + m[14]*uz;  gy = gy + m[22];
    float gz = m[15]*ux;  gz = gz + m[16]*uy;  gz = gz + m[17]*uz;  gz = gz + m[23];

    // voxelize f32: (geom - (BX - DX/2)) / DX; BX-DX/2 = {-50,-50,-10} exact f32
    float cx = (gx - (-50.0f)) / 0.5f;
    float cy = (gy - (-50.0f)) / 0.5f;
    float cz = (gz - (-10.0f)) / 20.0f;
    int g0 = (int)cx;   // trunc toward zero == astype(int32)
    int g1 = (int)cy;
    int g2 = (int)cz;

    bool kept = (g0 >= 0) && (g0 < NX0) && (g1 >= 0) && (g1 < NX1) && (g2 == 0);
    vox[p] = kept ? (b * (C_ * NX0 * NX1) + g0 * NX1 + g1) : -1;
}

// One wave (64 lanes) per point; lane = channel. Coalesced feature read,
// atomic scatter into out[b, c, g0, g1] (channel stride NX0*NX1).
__global__ void scatter_kernel(const float* __restrict__ x_feats,
                               const int* __restrict__ vox,
                               float* __restrict__ out) {
    int gid  = blockIdx.x * blockDim.x + threadIdx.x;
    int p    = gid >> 6;
    int lane = gid & 63;
    if (p >= NPRIME) return;
    int base = vox[p];
    if (base < 0) return;
    float v = x_feats[(size_t)p * C_ + lane];
    unsafeAtomicAdd(&out[base + lane * (NX0 * NX1)], v);
}

extern "C" void kernel_launch(void* const* d_in, const int* in_sizes, int n_in,
                              void* d_out, int out_size, void* d_ws, size_t ws_size,
                              hipStream_t stream) {
    const float* x_feats    = (const float*)d_in[0];
    const float* rots       = (const float*)d_in[1];
    const float* trans      = (const float*)d_in[2];
    const float* intrins    = (const float*)d_in[3];
    const float* post_rots  = (const float*)d_in[4];
    const float* post_trans = (const float*)d_in[5];
    float* out = (float*)d_out;

    float* mats = (float*)d_ws;                                    // 48*24*4 = 4608 B
    int*   vox  = (int*)((char*)d_ws + B_ * N_ * 24 * sizeof(float)); // 346368*4 B

    // 1) zero output
    zero_kernel<<<OUTSZ / 4 / 256, 256, 0, stream>>>((float4*)out, OUTSZ / 4);
    // 2) per-(b,n) matrices (f32, numpy-faithful)
    prep_kernel<<<1, 64, 0, stream>>>(rots, trans, intrins, post_rots, post_trans, mats);
    // 3) per-point voxel index
    geom_kernel<<<(NPRIME + 255) / 256, 256, 0, stream>>>(mats, vox);
    // 4) atomic scatter of features
    scatter_kernel<<<(NPRIME * 64) / 256, 256, 0, stream>>>(x_feats, vox, out);
}

// Round 4
// 329.615 us; speedup vs baseline: 1.2044x; 1.2044x over previous
//
#include <hip/hip_runtime.h>

// LiftSplatShoot dims
#define B_   8
#define N_   6
#define D_   41
#define FH_  8
#define FW_  22
#define C_   64
#define NPRIME (B_*N_*D_*FH_*FW_)   // 346368
#define NX0  200
#define NX1  200
#define NBUCKET (B_ * NX0)          // 1600 (b, g0) rows
#define OUTSZ (B_*C_*NX0*NX1)       // 20,480,000 floats

// ---------------- numpy-faithful fp32 3x3 inverse (LAPACK sgetrf+sgetri) ----
__device__ void lapack_inv3_f32(const float Ain[9], float Aout[9]) {
    #pragma clang fp contract(off)
    float a[9]; // column-major
    for (int r = 0; r < 3; ++r)
        for (int c = 0; c < 3; ++c)
            a[c*3 + r] = Ain[r*3 + c];
    int ipiv[3];
    for (int j = 0; j < 3; ++j) {
        int p = j;
        float amax = fabsf(a[j*3 + j]);
        for (int i = j + 1; i < 3; ++i) {
            float v = fabsf(a[j*3 + i]);
            if (v > amax) { amax = v; p = i; }
        }
        ipiv[j] = p;
        if (p != j)
            for (int c = 0; c < 3; ++c) { float t = a[c*3+j]; a[c*3+j] = a[c*3+p]; a[c*3+p] = t; }
        float d = 1.0f / a[j*3 + j];
        for (int i = j + 1; i < 3; ++i) a[j*3 + i] = a[j*3 + i] * d;
        for (int jj = j + 1; jj < 3; ++jj) {
            float temp = -a[jj*3 + j];
            for (int ii = j + 1; ii < 3; ++ii)
                a[jj*3 + ii] = a[jj*3 + ii] + a[j*3 + ii] * temp;
        }
    }
    for (int j = 0; j < 3; ++j) {
        float ajj_inv = 1.0f / a[j*3 + j];
        a[j*3 + j] = ajj_inv;
        float AJJ = -ajj_inv;
        for (int jj = 0; jj < j; ++jj) {
            float temp = a[j*3 + jj];
            for (int i = 0; i < jj; ++i)
                a[j*3 + i] = a[j*3 + i] + temp * a[jj*3 + i];
            a[j*3 + jj] = a[j*3 + jj] * a[jj*3 + jj];
        }
        for (int i = 0; i < j; ++i) a[j*3 + i] = a[j*3 + i] * AJJ;
    }
    float work[3];
    for (int j = 2; j >= 0; --j) {
        for (int i = j + 1; i < 3; ++i) { work[i] = a[j*3 + i]; a[j*3 + i] = 0.0f; }
        for (int jj = j + 1; jj < 3; ++jj) {
            float temp = -work[jj];
            for (int i = 0; i < 3; ++i)
                a[j*3 + i] = a[j*3 + i] + temp * a[jj*3 + i];
        }
    }
    for (int j = 2; j >= 0; --j) {
        int p = ipiv[j];
        if (p != j)
            for (int i = 0; i < 3; ++i) { float t = a[j*3+i]; a[j*3+i] = a[p*3+i]; a[p*3+i] = t; }
    }
    for (int r = 0; r < 3; ++r)
        for (int c = 0; c < 3; ++c)
            Aout[r*3 + c] = a[c*3 + r];
}

// prep (threads 0..47) + zero bucket counters (all 256 threads).
// mats per bn (24 floats): [invPR 0..8 | combine 9..17 | post_trans 18..20 | trans 21..23]
__global__ void prep_kernel(const float* __restrict__ rots,
                            const float* __restrict__ trans,
                            const float* __restrict__ intrins,
                            const float* __restrict__ post_rots,
                            const float* __restrict__ post_trans,
                            float* __restrict__ mats,
                            int* __restrict__ counts) {
    #pragma clang fp contract(off)
    int t = threadIdx.x;
    for (int i = t; i < NBUCKET; i += 256) counts[i] = 0;
    if (t >= B_ * N_) return;
    float pr[9], ipr[9], K[9], iK[9];
    for (int i = 0; i < 9; ++i) { pr[i] = post_rots[t*9 + i]; K[i] = intrins[t*9 + i]; }
    lapack_inv3_f32(pr, ipr);
    lapack_inv3_f32(K, iK);
    float* m = mats + t * 24;
    for (int i = 0; i < 9; ++i) m[i] = ipr[i];
    for (int i = 0; i < 3; ++i)
        for (int k = 0; k < 3; ++k) {
            float s = rots[t*9 + i*3 + 0] * iK[0*3 + k];
            s = s + rots[t*9 + i*3 + 1] * iK[1*3 + k];
            s = s + rots[t*9 + i*3 + 2] * iK[2*3 + k];
            m[9 + i*3 + k] = s;
        }
    for (int i = 0; i < 3; ++i) {
        m[18 + i] = post_trans[t*3 + i];
        m[21 + i] = trans[t*3 + i];
    }
}

// One thread per point: fp32 numpy-faithful geometry -> bucket (b,g0), packed
// (g1<<19 | p), histogram.
__global__ void geom_kernel(const float* __restrict__ mats,
                            unsigned short* __restrict__ pbucket,
                            unsigned int* __restrict__ pval,
                            int* __restrict__ counts) {
    #pragma clang fp contract(off)
    int p = blockIdx.x * blockDim.x + threadIdx.x;
    if (p >= NPRIME) return;
    int w  = p % FW_;
    int h  = (p / FW_) % FH_;
    int d  = (p / (FW_ * FH_)) % D_;
    int bn = p / (FW_ * FH_ * D_);
    int b  = bn / N_;

    const float* m = mats + bn * 24;

    float xs = (w == FW_ - 1) ? 351.0f : (float)((double)w * (351.0 / 21.0));
    float ys = (h == FH_ - 1) ? 127.0f : (float)((double)h * (127.0 / 7.0));
    float ds = 4.0f + (float)d;

    float px = xs - m[18], py = ys - m[19], pz = ds - m[20];
    float qx = m[0]*px;  qx = qx + m[1]*py;  qx = qx + m[2]*pz;
    float qy = m[3]*px;  qy = qy + m[4]*py;  qy = qy + m[5]*pz;
    float qz = m[6]*px;  qz = qz + m[7]*py;  qz = qz + m[8]*pz;

    float ux = qx * qz, uy = qy * qz, uz = qz;

    float gx = m[9]*ux;   gx = gx + m[10]*uy;  gx = gx + m[11]*uz;  gx = gx + m[21];
    float gy = m[12]*ux;  gy = gy + m[13]*uy;  gy = gy + m[14]*uz;  gy = gy + m[22];
    float gz = m[15]*ux;  gz = gz + m[16]*uy;  gz = gz + m[17]*uz;  gz = gz + m[23];

    float cx = (gx - (-50.0f)) / 0.5f;
    float cy = (gy - (-50.0f)) / 0.5f;
    float cz = (gz - (-10.0f)) / 20.0f;
    int g0 = (int)cx;
    int g1 = (int)cy;
    int g2 = (int)cz;

    bool kept = (g0 >= 0) && (g0 < NX0) && (g1 >= 0) && (g1 < NX1) && (g2 == 0);
    if (kept) {
        int bk = b * NX0 + g0;
        pbucket[p] = (unsigned short)bk;
        pval[p]    = ((unsigned int)g1 << 19) | (unsigned int)p;
        atomicAdd(&counts[bk], 1);
    } else {
        pbucket[p] = 0xFFFFu;
        pval[p]    = 0u;
    }
}

// Single-block exclusive scan over 1600 bucket counts -> offsets[0..1600], cursor.
__global__ void scan_kernel(const int* __restrict__ counts,
                            int* __restrict__ offsets,
                            int* __restrict__ cursor) {
    __shared__ int ts[256];
    int t = threadIdx.x;
    const int PER = 7; // 7*256 = 1792 >= 1600
    int mysum = 0;
    for (int j = 0; j < PER; ++j) {
        int idx = t * PER + j;
        if (idx < NBUCKET) mysum += counts[idx];
    }
    ts[t] = mysum;
    __syncthreads();
    for (int off = 1; off < 256; off <<= 1) {
        int v = (t >= off) ? ts[t - off] : 0;
        __syncthreads();
        ts[t] += v;
        __syncthreads();
    }
    int run = (t > 0) ? ts[t - 1] : 0;  // exclusive base
    for (int j = 0; j < PER; ++j) {
        int idx = t * PER + j;
        if (idx <= NBUCKET) {
            offsets[idx] = run;
            if (idx < NBUCKET) {
                cursor[idx] = run;
                run += counts[idx];
            }
        }
    }
}

// Compact kept points into per-bucket segments.
__global__ void place_kernel(const unsigned short* __restrict__ pbucket,
                             const unsigned int* __restrict__ pval,
                             int* __restrict__ cursor,
                             unsigned int* __restrict__ entries) {
    int p = blockIdx.x * blockDim.x + threadIdx.x;
    if (p >= NPRIME) return;
    unsigned short bk = pbucket[p];
    if (bk == 0xFFFFu) return;
    int pos = atomicAdd(&cursor[bk], 1);
    entries[pos] = pval[p];
}

// One workgroup per (b, g0) output row: LDS-accumulate 64ch x 200 voxels,
// then fully-coalesced row write (also serves as the zero-fill).
#define LDS_STRIDE 201   // 201 % 32 = 9, gcd(9,32)=1 -> conflict-free lane=ch access
__global__ void __launch_bounds__(256) gather_kernel(
        const float* __restrict__ x_feats,
        const unsigned int* __restrict__ entries,
        const int* __restrict__ offsets,
        float* __restrict__ out) {
    __shared__ float acc[C_ * LDS_STRIDE]; // 51456 B
    int bid = blockIdx.x;           // b*200 + g0
    int b   = bid / NX0;
    int g0  = bid % NX0;
    int t   = threadIdx.x;
    int wave = t >> 6;
    int lane = t & 63;

    for (int i = t; i < C_ * LDS_STRIDE; i += 256) acc[i] = 0.0f;
    __syncthreads();

    int s = offsets[bid], e = offsets[bid + 1];
    for (int i = s + wave; i < e; i += 4) {
        unsigned int v = entries[i];
        int g1 = (int)(v >> 19);
        int p  = (int)(v & 0x7FFFFu);
        float f = x_feats[(size_t)p * C_ + lane];
        atomicAdd(&acc[lane * LDS_STRIDE + g1], f);
    }
    __syncthreads();

    // write out[b][c][g0][0..199], coalesced 200-float rows
    size_t rowbase = (((size_t)b * C_) * NX0 + g0) * NX1;
    for (int i = t; i < C_ * NX1; i += 256) {
        int c  = i / NX1;
        int g1 = i % NX1;
        out[rowbase + (size_t)c * (NX0 * NX1) + g1] = acc[c * LDS_STRIDE + g1];
    }
}

extern "C" void kernel_launch(void* const* d_in, const int* in_sizes, int n_in,
                              void* d_out, int out_size, void* d_ws, size_t ws_size,
                              hipStream_t stream) {
    const float* x_feats    = (const float*)d_in[0];
    const float* rots       = (const float*)d_in[1];
    const float* trans      = (const float*)d_in[2];
    const float* intrins    = (const float*)d_in[3];
    const float* post_rots  = (const float*)d_in[4];
    const float* post_trans = (const float*)d_in[5];
    float* out = (float*)d_out;

    // ws layout
    char* w = (char*)d_ws;
    float*          mats    = (float*)w;              w += 48 * 24 * sizeof(float);      // 4608 B
    int*            counts  = (int*)w;                w += NBUCKET * sizeof(int);
    int*            offsets = (int*)w;                w += (NBUCKET + 1) * sizeof(int);
    int*            cursor  = (int*)w;                w += NBUCKET * sizeof(int);
    unsigned short* pbucket = (unsigned short*)w;     w += NPRIME * sizeof(unsigned short);
    w = (char*)(((size_t)w + 3) & ~(size_t)3);
    unsigned int*   pval    = (unsigned int*)w;       w += NPRIME * sizeof(unsigned int);
    unsigned int*   entries = (unsigned int*)w;       w += NPRIME * sizeof(unsigned int);

    prep_kernel<<<1, 256, 0, stream>>>(rots, trans, intrins, post_rots, post_trans,
                                       mats, counts);
    geom_kernel<<<(NPRIME + 255) / 256, 256, 0, stream>>>(mats, pbucket, pval, counts);
    scan_kernel<<<1, 256, 0, stream>>>(counts, offsets, cursor);
    place_kernel<<<(NPRIME + 255) / 256, 256, 0, stream>>>(pbucket, pval, cursor, entries);
    gather_kernel<<<NBUCKET, 256, 0, stream>>>(x_feats, entries, offsets, out);
}

// Round 5
// 262.692 us; speedup vs baseline: 1.5113x; 1.2548x over previous
//
#include <hip/hip_runtime.h>

// LiftSplatShoot dims
#define B_   8
#define N_   6
#define D_   41
#define FH_  8
#define FW_  22
#define C_   64
#define NPRIME (B_*N_*D_*FH_*FW_)   // 346368
#define NX0  200
#define NX1  200
#define G1Q  4                      // g1 quarters of 50
#define NB2  (B_ * NX0 * G1Q)       // 6400 buckets (b, g0, g1/50)
#define OUTSZ (B_*C_*NX0*NX1)       // 20,480,000 floats

// ---------------- numpy-faithful fp32 3x3 inverse (LAPACK sgetrf+sgetri) ----
__device__ void lapack_inv3_f32(const float Ain[9], float Aout[9]) {
    #pragma clang fp contract(off)
    float a[9]; // column-major
    for (int r = 0; r < 3; ++r)
        for (int c = 0; c < 3; ++c)
            a[c*3 + r] = Ain[r*3 + c];
    int ipiv[3];
    for (int j = 0; j < 3; ++j) {
        int p = j;
        float amax = fabsf(a[j*3 + j]);
        for (int i = j + 1; i < 3; ++i) {
            float v = fabsf(a[j*3 + i]);
            if (v > amax) { amax = v; p = i; }
        }
        ipiv[j] = p;
        if (p != j)
            for (int c = 0; c < 3; ++c) { float t = a[c*3+j]; a[c*3+j] = a[c*3+p]; a[c*3+p] = t; }
        float d = 1.0f / a[j*3 + j];
        for (int i = j + 1; i < 3; ++i) a[j*3 + i] = a[j*3 + i] * d;
        for (int jj = j + 1; jj < 3; ++jj) {
            float temp = -a[jj*3 + j];
            for (int ii = j + 1; ii < 3; ++ii)
                a[jj*3 + ii] = a[jj*3 + ii] + a[j*3 + ii] * temp;
        }
    }
    for (int j = 0; j < 3; ++j) {
        float ajj_inv = 1.0f / a[j*3 + j];
        a[j*3 + j] = ajj_inv;
        float AJJ = -ajj_inv;
        for (int jj = 0; jj < j; ++jj) {
            float temp = a[j*3 + jj];
            for (int i = 0; i < jj; ++i)
                a[j*3 + i] = a[j*3 + i] + temp * a[jj*3 + i];
            a[j*3 + jj] = a[j*3 + jj] * a[jj*3 + jj];
        }
        for (int i = 0; i < j; ++i) a[j*3 + i] = a[j*3 + i] * AJJ;
    }
    float work[3];
    for (int j = 2; j >= 0; --j) {
        for (int i = j + 1; i < 3; ++i) { work[i] = a[j*3 + i]; a[j*3 + i] = 0.0f; }
        for (int jj = j + 1; jj < 3; ++jj) {
            float temp = -work[jj];
            for (int i = 0; i < 3; ++i)
                a[j*3 + i] = a[j*3 + i] + temp * a[jj*3 + i];
        }
    }
    for (int j = 2; j >= 0; --j) {
        int p = ipiv[j];
        if (p != j)
            for (int i = 0; i < 3; ++i) { float t = a[j*3+i]; a[j*3+i] = a[p*3+i]; a[p*3+i] = t; }
    }
    for (int r = 0; r < 3; ++r)
        for (int c = 0; c < 3; ++c)
            Aout[r*3 + c] = a[c*3 + r];
}

// prep (threads 0..47) + zero bucket counters.
// mats per bn (24 floats): [invPR 0..8 | combine 9..17 | post_trans 18..20 | trans 21..23]
__global__ void prep_kernel(const float* __restrict__ rots,
                            const float* __restrict__ trans,
                            const float* __restrict__ intrins,
                            const float* __restrict__ post_rots,
                            const float* __restrict__ post_trans,
                            float* __restrict__ mats,
                            int* __restrict__ counts) {
    #pragma clang fp contract(off)
    int t = threadIdx.x;
    for (int i = t; i < NB2; i += 256) counts[i] = 0;
    if (t >= B_ * N_) return;
    float pr[9], ipr[9], K[9], iK[9];
    for (int i = 0; i < 9; ++i) { pr[i] = post_rots[t*9 + i]; K[i] = intrins[t*9 + i]; }
    lapack_inv3_f32(pr, ipr);
    lapack_inv3_f32(K, iK);
    float* m = mats + t * 24;
    for (int i = 0; i < 9; ++i) m[i] = ipr[i];
    for (int i = 0; i < 3; ++i)
        for (int k = 0; k < 3; ++k) {
            float s = rots[t*9 + i*3 + 0] * iK[0*3 + k];
            s = s + rots[t*9 + i*3 + 1] * iK[1*3 + k];
            s = s + rots[t*9 + i*3 + 2] * iK[2*3 + k];
            m[9 + i*3 + k] = s;
        }
    for (int i = 0; i < 3; ++i) {
        m[18 + i] = post_trans[t*3 + i];
        m[21 + i] = trans[t*3 + i];
    }
}

// One thread per point: fp32 numpy-faithful geometry -> pcode = (bk<<6)|g1r
// (p implicit in index), histogram over 6400 buckets.
__global__ void geom_kernel(const float* __restrict__ mats,
                            unsigned int* __restrict__ pcode,
                            int* __restrict__ counts) {
    #pragma clang fp contract(off)
    int p = blockIdx.x * blockDim.x + threadIdx.x;
    if (p >= NPRIME) return;
    int w  = p % FW_;
    int h  = (p / FW_) % FH_;
    int d  = (p / (FW_ * FH_)) % D_;
    int bn = p / (FW_ * FH_ * D_);
    int b  = bn / N_;

    const float* m = mats + bn * 24;

    float xs = (w == FW_ - 1) ? 351.0f : (float)((double)w * (351.0 / 21.0));
    float ys = (h == FH_ - 1) ? 127.0f : (float)((double)h * (127.0 / 7.0));
    float ds = 4.0f + (float)d;

    float px = xs - m[18], py = ys - m[19], pz = ds - m[20];
    float qx = m[0]*px;  qx = qx + m[1]*py;  qx = qx + m[2]*pz;
    float qy = m[3]*px;  qy = qy + m[4]*py;  qy = qy + m[5]*pz;
    float qz = m[6]*px;  qz = qz + m[7]*py;  qz = qz + m[8]*pz;

    float ux = qx * qz, uy = qy * qz, uz = qz;

    float gx = m[9]*ux;   gx = gx + m[10]*uy;  gx = gx + m[11]*uz;  gx = gx + m[21];
    float gy = m[12]*ux;  gy = gy + m[13]*uy;  gy = gy + m[14]*uz;  gy = gy + m[22];
    float gz = m[15]*ux;  gz = gz + m[16]*uy;  gz = gz + m[17]*uz;  gz = gz + m[23];

    float cx = (gx - (-50.0f)) / 0.5f;
    float cy = (gy - (-50.0f)) / 0.5f;
    float cz = (gz - (-10.0f)) / 20.0f;
    int g0 = (int)cx;
    int g1 = (int)cy;
    int g2 = (int)cz;

    bool kept = (g0 >= 0) && (g0 < NX0) && (g1 >= 0) && (g1 < NX1) && (g2 == 0);
    if (kept) {
        int g1q = g1 / 50;
        int g1r = g1 - g1q * 50;
        int bk  = (b * NX0 + g0) * G1Q + g1q;
        pcode[p] = ((unsigned int)bk << 6) | (unsigned int)g1r;
        atomicAdd(&counts[bk], 1);
    } else {
        pcode[p] = 0xFFFFFFFFu;
    }
}

// Single-block exclusive scan over 6400 bucket counts -> offsets[0..6400], cursor.
__global__ void scan_kernel(const int* __restrict__ counts,
                            int* __restrict__ offsets,
                            int* __restrict__ cursor) {
    __shared__ int ts[256];
    int t = threadIdx.x;
    const int PER = NB2 / 256; // 25
    int base = t * PER;
    int mysum = 0;
    for (int j = 0; j < PER; ++j) mysum += counts[base + j];
    ts[t] = mysum;
    __syncthreads();
    for (int off = 1; off < 256; off <<= 1) {
        int v = (t >= off) ? ts[t - off] : 0;
        __syncthreads();
        ts[t] += v;
        __syncthreads();
    }
    int run = (t > 0) ? ts[t - 1] : 0;  // exclusive base
    for (int j = 0; j < PER; ++j) {
        offsets[base + j] = run;
        cursor[base + j]  = run;
        run += counts[base + j];
    }
    if (t == 255) offsets[NB2] = run;
}

// Compact kept points into per-bucket segments. entries = (g1r<<19)|p.
__global__ void place_kernel(const unsigned int* __restrict__ pcode,
                             int* __restrict__ cursor,
                             unsigned int* __restrict__ entries) {
    int p = blockIdx.x * blockDim.x + threadIdx.x;
    if (p >= NPRIME) return;
    unsigned int code = pcode[p];
    if (code == 0xFFFFFFFFu) return;
    int bk  = (int)(code >> 6);
    int g1r = (int)(code & 63u);
    int pos = atomicAdd(&cursor[bk], 1);
    entries[pos] = ((unsigned int)g1r << 19) | (unsigned int)p;
}

// One workgroup (8 waves) per bucket = (b, g0, 50-wide g1 quarter).
// LDS-accumulate 64ch x 50 voxels with 4-entry ILP, then coalesced write.
#define LDS_STRIDE 51   // (lane*51)%32: gcd(19,32)=1 -> 2 lanes/bank, free
__global__ void __launch_bounds__(512) gather_kernel(
        const float* __restrict__ x_feats,
        const unsigned int* __restrict__ entries,
        const int* __restrict__ offsets,
        float* __restrict__ out) {
    __shared__ float acc[C_ * LDS_STRIDE]; // 13056 B
    int bid = blockIdx.x;            // (b*200 + g0)*4 + g1q
    int b   = bid / (NX0 * G1Q);
    int rem = bid % (NX0 * G1Q);
    int g0  = rem / G1Q;
    int g1q = rem % G1Q;
    int t    = threadIdx.x;
    int wave = t >> 6;
    int lane = t & 63;

    size_t obase = (size_t)b * (C_ * NX0 * NX1) + (size_t)g0 * NX1 + g1q * 50;

    int s = offsets[bid], e = offsets[bid + 1];

    if (s == e) {
        // empty bucket: stream zeros, no LDS round-trip
        for (int i = t; i < C_ * 50; i += 512) {
            int c = i / 50, r = i - c * 50;
            out[obase + (size_t)c * (NX0 * NX1) + r] = 0.0f;
        }
        return;
    }

    for (int i = t; i < C_ * LDS_STRIDE; i += 512) acc[i] = 0.0f;
    __syncthreads();

    // each wave owns chunks of 4 consecutive entries, stride 32 (8 waves * 4)
    int i = s + wave * 4;
    for (; i + 4 <= e; i += 32) {
        unsigned int v0 = entries[i];
        unsigned int v1 = entries[i + 1];
        unsigned int v2 = entries[i + 2];
        unsigned int v3 = entries[i + 3];
        float f0 = x_feats[(size_t)(v0 & 0x7FFFFu) * C_ + lane];
        float f1 = x_feats[(size_t)(v1 & 0x7FFFFu) * C_ + lane];
        float f2 = x_feats[(size_t)(v2 & 0x7FFFFu) * C_ + lane];
        float f3 = x_feats[(size_t)(v3 & 0x7FFFFu) * C_ + lane];
        atomicAdd(&acc[lane * LDS_STRIDE + (int)(v0 >> 19)], f0);
        atomicAdd(&acc[lane * LDS_STRIDE + (int)(v1 >> 19)], f1);
        atomicAdd(&acc[lane * LDS_STRIDE + (int)(v2 >> 19)], f2);
        atomicAdd(&acc[lane * LDS_STRIDE + (int)(v3 >> 19)], f3);
    }
    for (; i < e; ++i) {  // partial last chunk of this wave
        unsigned int v = entries[i];
        float f = x_feats[(size_t)(v & 0x7FFFFu) * C_ + lane];
        atomicAdd(&acc[lane * LDS_STRIDE + (int)(v >> 19)], f);
    }
    __syncthreads();

    for (int k = t; k < C_ * 50; k += 512) {
        int c = k / 50, r = k - c * 50;
        out[obase + (size_t)c * (NX0 * NX1) + r] = acc[c * LDS_STRIDE + r];
    }
}

extern "C" void kernel_launch(void* const* d_in, const int* in_sizes, int n_in,
                              void* d_out, int out_size, void* d_ws, size_t ws_size,
                              hipStream_t stream) {
    const float* x_feats    = (const float*)d_in[0];
    const float* rots       = (const float*)d_in[1];
    const float* trans      = (const float*)d_in[2];
    const float* intrins    = (const float*)d_in[3];
    const float* post_rots  = (const float*)d_in[4];
    const float* post_trans = (const float*)d_in[5];
    float* out = (float*)d_out;

    // ws layout
    char* w = (char*)d_ws;
    float*        mats    = (float*)w;         w += 48 * 24 * sizeof(float);
    int*          counts  = (int*)w;           w += NB2 * sizeof(int);
    int*          offsets = (int*)w;           w += (NB2 + 1) * sizeof(int);
    int*          cursor  = (int*)w;           w += NB2 * sizeof(int);
    unsigned int* pcode   = (unsigned int*)w;  w += NPRIME * sizeof(unsigned int);
    unsigned int* entries = (unsigned int*)w;  w += NPRIME * sizeof(unsigned int);

    prep_kernel<<<1, 256, 0, stream>>>(rots, trans, intrins, post_rots, post_trans,
                                       mats, counts);
    geom_kernel<<<(NPRIME + 255) / 256, 256, 0, stream>>>(mats, pcode, counts);
    scan_kernel<<<1, 256, 0, stream>>>(counts, offsets, cursor);
    place_kernel<<<(NPRIME + 255) / 256, 256, 0, stream>>>(pcode, cursor, entries);
    gather_kernel<<<NB2, 512, 0, stream>>>(x_feats, entries, offsets, out);
}

// Round 6
// 224.138 us; speedup vs baseline: 1.7712x; 1.1720x over previous
//
#include <hip/hip_runtime.h>

// LiftSplatShoot dims
#define B_   8
#define N_   6
#define D_   41
#define FH_  8
#define FW_  22
#define C_   64
#define NPRIME (B_*N_*D_*FH_*FW_)   // 346368 = 1353 * 256 exactly
#define NBLK_PTS 1353
#define NX0  200
#define NX1  200
#define G1Q  4                      // g1 quarters of 50
#define NB2  (B_ * NX0 * G1Q)       // 6400 buckets (b, g0, g1/50)
#define OUTSZ (B_*C_*NX0*NX1)       // 20,480,000 floats
#define CAP  512                    // max entries per gather task
#define DIRECT_N 16                 // small-task direct-atomic path
#define MAXTASKS 8192

// ---------------- numpy-faithful fp32 3x3 inverse (LAPACK sgetrf+sgetri) ----
__device__ void lapack_inv3_f32(const float Ain[9], float Aout[9]) {
    #pragma clang fp contract(off)
    float a[9]; // column-major
    for (int r = 0; r < 3; ++r)
        for (int c = 0; c < 3; ++c)
            a[c*3 + r] = Ain[r*3 + c];
    int ipiv[3];
    for (int j = 0; j < 3; ++j) {
        int p = j;
        float amax = fabsf(a[j*3 + j]);
        for (int i = j + 1; i < 3; ++i) {
            float v = fabsf(a[j*3 + i]);
            if (v > amax) { amax = v; p = i; }
        }
        ipiv[j] = p;
        if (p != j)
            for (int c = 0; c < 3; ++c) { float t = a[c*3+j]; a[c*3+j] = a[c*3+p]; a[c*3+p] = t; }
        float d = 1.0f / a[j*3 + j];
        for (int i = j + 1; i < 3; ++i) a[j*3 + i] = a[j*3 + i] * d;
        for (int jj = j + 1; jj < 3; ++jj) {
            float temp = -a[jj*3 + j];
            for (int ii = j + 1; ii < 3; ++ii)
                a[jj*3 + ii] = a[jj*3 + ii] + a[j*3 + ii] * temp;
        }
    }
    for (int j = 0; j < 3; ++j) {
        float ajj_inv = 1.0f / a[j*3 + j];
        a[j*3 + j] = ajj_inv;
        float AJJ = -ajj_inv;
        for (int jj = 0; jj < j; ++jj) {
            float temp = a[j*3 + jj];
            for (int i = 0; i < jj; ++i)
                a[j*3 + i] = a[j*3 + i] + temp * a[jj*3 + i];
            a[j*3 + jj] = a[j*3 + jj] * a[jj*3 + jj];
        }
        for (int i = 0; i < j; ++i) a[j*3 + i] = a[j*3 + i] * AJJ;
    }
    float work[3];
    for (int j = 2; j >= 0; --j) {
        for (int i = j + 1; i < 3; ++i) { work[i] = a[j*3 + i]; a[j*3 + i] = 0.0f; }
        for (int jj = j + 1; jj < 3; ++jj) {
            float temp = -work[jj];
            for (int i = 0; i < 3; ++i)
                a[j*3 + i] = a[j*3 + i] + temp * a[jj*3 + i];
        }
    }
    for (int j = 2; j >= 0; --j) {
        int p = ipiv[j];
        if (p != j)
            for (int i = 0; i < 3; ++i) { float t = a[j*3+i]; a[j*3+i] = a[p*3+i]; a[p*3+i] = t; }
    }
    for (int r = 0; r < 3; ++r)
        for (int c = 0; c < 3; ++c)
            Aout[r*3 + c] = a[c*3 + r];
}

// prep (threads 0..47) + zero bucket counters + task counter.
__global__ void prep_kernel(const float* __restrict__ rots,
                            const float* __restrict__ trans,
                            const float* __restrict__ intrins,
                            const float* __restrict__ post_rots,
                            const float* __restrict__ post_trans,
                            float* __restrict__ mats,
                            int* __restrict__ counts,
                            int* __restrict__ task_count) {
    #pragma clang fp contract(off)
    int t = threadIdx.x;
    for (int i = t; i < NB2; i += 256) counts[i] = 0;
    if (t == 0) task_count[0] = 0;
    if (t >= B_ * N_) return;
    float pr[9], ipr[9], K[9], iK[9];
    for (int i = 0; i < 9; ++i) { pr[i] = post_rots[t*9 + i]; K[i] = intrins[t*9 + i]; }
    lapack_inv3_f32(pr, ipr);
    lapack_inv3_f32(K, iK);
    float* m = mats + t * 24;
    for (int i = 0; i < 9; ++i) m[i] = ipr[i];
    for (int i = 0; i < 3; ++i)
        for (int k = 0; k < 3; ++k) {
            float s = rots[t*9 + i*3 + 0] * iK[0*3 + k];
            s = s + rots[t*9 + i*3 + 1] * iK[1*3 + k];
            s = s + rots[t*9 + i*3 + 2] * iK[2*3 + k];
            m[9 + i*3 + k] = s;
        }
    for (int i = 0; i < 3; ++i) {
        m[18 + i] = post_trans[t*3 + i];
        m[21 + i] = trans[t*3 + i];
    }
}

// One thread per point (grid exact): fp32 numpy-faithful geometry ->
// pcode=(bk<<6)|g1r; block-local LDS histogram -> hierarchical flush.
// Also grid-stride zeroes the output (out poisoned each launch).
__global__ void __launch_bounds__(256) geom_kernel(
        const float* __restrict__ mats,
        unsigned int* __restrict__ pcode,
        int* __restrict__ counts,
        float4* __restrict__ out4) {
    #pragma clang fp contract(off)
    __shared__ unsigned int hist[NB2];   // 25.6 KB
    int t = threadIdx.x;
    int p = blockIdx.x * 256 + t;
    for (int i = t; i < NB2; i += 256) hist[i] = 0u;
    __syncthreads();

    int w  = p % FW_;
    int h  = (p / FW_) % FH_;
    int d  = (p / (FW_ * FH_)) % D_;
    int bn = p / (FW_ * FH_ * D_);
    int b  = bn / N_;

    const float* m = mats + bn * 24;

    float xs = (w == FW_ - 1) ? 351.0f : (float)((double)w * (351.0 / 21.0));
    float ys = (h == FH_ - 1) ? 127.0f : (float)((double)h * (127.0 / 7.0));
    float ds = 4.0f + (float)d;

    float px = xs - m[18], py = ys - m[19], pz = ds - m[20];
    float qx = m[0]*px;  qx = qx + m[1]*py;  qx = qx + m[2]*pz;
    float qy = m[3]*px;  qy = qy + m[4]*py;  qy = qy + m[5]*pz;
    float qz = m[6]*px;  qz = qz + m[7]*py;  qz = qz + m[8]*pz;

    float ux = qx * qz, uy = qy * qz, uz = qz;

    float gx = m[9]*ux;   gx = gx + m[10]*uy;  gx = gx + m[11]*uz;  gx = gx + m[21];
    float gy = m[12]*ux;  gy = gy + m[13]*uy;  gy = gy + m[14]*uz;  gy = gy + m[22];
    float gz = m[15]*ux;  gz = gz + m[16]*uy;  gz = gz + m[17]*uz;  gz = gz + m[23];

    float cx = (gx - (-50.0f)) / 0.5f;
    float cy = (gy - (-50.0f)) / 0.5f;
    float cz = (gz - (-10.0f)) / 20.0f;
    int g0 = (int)cx;
    int g1 = (int)cy;
    int g2 = (int)cz;

    bool kept = (g0 >= 0) && (g0 < NX0) && (g1 >= 0) && (g1 < NX1) && (g2 == 0);
    if (kept) {
        int g1q = g1 / 50;
        int g1r = g1 - g1q * 50;
        int bk  = (b * NX0 + g0) * G1Q + g1q;
        pcode[p] = ((unsigned int)bk << 6) | (unsigned int)g1r;
        atomicAdd(&hist[bk], 1u);
    } else {
        pcode[p] = 0xFFFFFFFFu;
    }
    __syncthreads();
    for (int i = t; i < NB2; i += 256) {
        unsigned int hv = hist[i];
        if (hv) atomicAdd(&counts[i], (int)hv);
    }

    // zero the output grid (float4 streaming)
    const int TOT4 = OUTSZ / 4;
    float4 z4 = make_float4(0.f, 0.f, 0.f, 0.f);
    for (int i = p; i < TOT4; i += NPRIME) out4[i] = z4;
}

// Single-block exclusive scan over 6400 counts -> offsets, cursor; emit
// size-capped tasks: bit31=sole, bits[9:22)=bucket, bits[0:9)=chunk.
__global__ void scan_kernel(const int* __restrict__ counts,
                            int* __restrict__ offsets,
                            int* __restrict__ cursor,
                            unsigned int* __restrict__ tasks,
                            int* __restrict__ task_count) {
    __shared__ int ts[256];
    int t = threadIdx.x;
    const int PER = NB2 / 256; // 25
    int base = t * PER;
    int mysum = 0;
    for (int j = 0; j < PER; ++j) mysum += counts[base + j];
    ts[t] = mysum;
    __syncthreads();
    for (int off = 1; off < 256; off <<= 1) {
        int v = (t >= off) ? ts[t - off] : 0;
        __syncthreads();
        ts[t] += v;
        __syncthreads();
    }
    int run = (t > 0) ? ts[t - 1] : 0;  // exclusive base
    int ltasks = 0;
    for (int j = 0; j < PER; ++j) {
        int c = counts[base + j];
        offsets[base + j] = run;
        cursor[base + j]  = run;
        run += c;
        if (c > 0) ltasks += (c + CAP - 1) / CAP;
    }
    if (t == 255) offsets[NB2] = run;
    int tpos = (ltasks > 0) ? atomicAdd(task_count, ltasks) : 0;
    for (int j = 0; j < PER; ++j) {
        int c = counts[base + j];
        if (c <= 0) continue;
        int nch = (c + CAP - 1) / CAP;
        unsigned int sole = (nch == 1) ? (1u << 31) : 0u;
        for (int k = 0; k < nch; ++k)
            tasks[tpos++] = sole | ((unsigned int)(base + j) << 9) | (unsigned int)k;
    }
}

// Compact kept points: block-aggregated reservation (one global atomic per
// block x touched-bucket), local ranks via LDS atomics.
__global__ void __launch_bounds__(256) place_kernel(
        const unsigned int* __restrict__ pcode,
        int* __restrict__ cursor,
        unsigned int* __restrict__ entries) {
    __shared__ unsigned int cnt[NB2];   // 25.6 KB
    __shared__ int gbase[NB2];          // 25.6 KB
    int t = threadIdx.x;
    int p = blockIdx.x * 256 + t;
    for (int i = t; i < NB2; i += 256) cnt[i] = 0u;
    __syncthreads();
    unsigned int code = pcode[p];
    bool kept = (code != 0xFFFFFFFFu);
    int bk = (int)(code >> 6);
    unsigned int lr = 0;
    if (kept) lr = atomicAdd(&cnt[bk], 1u);
    __syncthreads();
    for (int i = t; i < NB2; i += 256) {
        unsigned int c = cnt[i];
        if (c) gbase[i] = atomicAdd(&cursor[i], (int)c);
    }
    __syncthreads();
    if (kept)
        entries[gbase[bk] + (int)lr] = ((code & 63u) << 19) | (unsigned int)p;
}

// Task-indexed gather: one block per (bucket, <=512-entry chunk).
// Out is pre-zeroed; sole tasks store, multi-chunk tasks atomic-flush,
// tiny tasks bypass LDS with direct global atomics.
#define LDS_STRIDE 51
__global__ void __launch_bounds__(512) gather_kernel(
        const float* __restrict__ x_feats,
        const unsigned int* __restrict__ entries,
        const int* __restrict__ offsets,
        const unsigned int* __restrict__ tasks,
        const int* __restrict__ task_count,
        float* __restrict__ out) {
    __shared__ float acc[C_ * LDS_STRIDE]; // 13056 B
    __shared__ unsigned int ecache[CAP];   // 2 KB
    __shared__ int touched[50];
    int bid = blockIdx.x;
    if (bid >= task_count[0]) return;
    unsigned int task = tasks[bid];
    int sole = (int)(task >> 31);
    int bk   = (int)((task >> 9) & 0x1FFFu);
    int ch   = (int)(task & 0x1FFu);
    int s = offsets[bk] + ch * CAP;
    int e = offsets[bk + 1];
    if (e > s + CAP) e = s + CAP;
    int n = e - s;

    int t = threadIdx.x, wave = t >> 6, lane = t & 63;
    int b   = bk / (NX0 * G1Q);
    int rem = bk % (NX0 * G1Q);
    int g0  = rem / G1Q, g1q = rem % G1Q;
    size_t obase = (size_t)b * (C_ * NX0 * NX1) + (size_t)g0 * NX1 + g1q * 50;

    if (n <= DIRECT_N) {
        for (int i = wave; i < n; i += 8) {
            unsigned int v = entries[s + i];
            float f = x_feats[(size_t)(v & 0x7FFFFu) * C_ + lane];
            unsafeAtomicAdd(&out[obase + (size_t)lane * (NX0 * NX1) + (int)(v >> 19)], f);
        }
        return;
    }

    for (int i = t; i < C_ * LDS_STRIDE; i += 512) acc[i] = 0.0f;
    if (t < 50) touched[t] = 0;
    if (t < n) ecache[t] = entries[s + t];
    __syncthreads();

    int i = wave * 4;
    for (; i + 4 <= n; i += 32) {
        unsigned int v0 = ecache[i],     v1 = ecache[i + 1];
        unsigned int v2 = ecache[i + 2], v3 = ecache[i + 3];
        float f0 = x_feats[(size_t)(v0 & 0x7FFFFu) * C_ + lane];
        float f1 = x_feats[(size_t)(v1 & 0x7FFFFu) * C_ + lane];
        float f2 = x_feats[(size_t)(v2 & 0x7FFFFu) * C_ + lane];
        float f3 = x_feats[(size_t)(v3 & 0x7FFFFu) * C_ + lane];
        if (lane == 0) {
            touched[v0 >> 19] = 1; touched[v1 >> 19] = 1;
            touched[v2 >> 19] = 1; touched[v3 >> 19] = 1;
        }
        atomicAdd(&acc[lane * LDS_STRIDE + (int)(v0 >> 19)], f0);
        atomicAdd(&acc[lane * LDS_STRIDE + (int)(v1 >> 19)], f1);
        atomicAdd(&acc[lane * LDS_STRIDE + (int)(v2 >> 19)], f2);
        atomicAdd(&acc[lane * LDS_STRIDE + (int)(v3 >> 19)], f3);
    }
    for (; i < n; ++i) {
        unsigned int v = ecache[i];
        float f = x_feats[(size_t)(v & 0x7FFFFu) * C_ + lane];
        if (lane == 0) touched[v >> 19] = 1;
        atomicAdd(&acc[lane * LDS_STRIDE + (int)(v >> 19)], f);
    }
    __syncthreads();

    for (int k = t; k < C_ * 50; k += 512) {
        int c = k / 50, r = k - c * 50;
        if (!touched[r]) continue;
        float val = acc[c * LDS_STRIDE + r];
        if (val != 0.0f) {
            float* dst = &out[obase + (size_t)c * (NX0 * NX1) + r];
            if (sole) *dst = val;
            else unsafeAtomicAdd(dst, val);
        }
    }
}

extern "C" void kernel_launch(void* const* d_in, const int* in_sizes, int n_in,
                              void* d_out, int out_size, void* d_ws, size_t ws_size,
                              hipStream_t stream) {
    const float* x_feats    = (const float*)d_in[0];
    const float* rots       = (const float*)d_in[1];
    const float* trans      = (const float*)d_in[2];
    const float* intrins    = (const float*)d_in[3];
    const float* post_rots  = (const float*)d_in[4];
    const float* post_trans = (const float*)d_in[5];
    float* out = (float*)d_out;

    // ws layout (~2.9 MB)
    char* w = (char*)d_ws;
    float*        mats       = (float*)w;         w += 48 * 24 * sizeof(float);
    int*          counts     = (int*)w;           w += NB2 * sizeof(int);
    int*          offsets    = (int*)w;           w += (NB2 + 1) * sizeof(int);
    int*          cursor     = (int*)w;           w += NB2 * sizeof(int);
    int*          task_count = (int*)w;           w += 4 * sizeof(int); // padded
    unsigned int* tasks      = (unsigned int*)w;  w += MAXTASKS * sizeof(unsigned int);
    unsigned int* pcode      = (unsigned int*)w;  w += NPRIME * sizeof(unsigned int);
    unsigned int* entries    = (unsigned int*)w;  w += NPRIME * sizeof(unsigned int);

    prep_kernel<<<1, 256, 0, stream>>>(rots, trans, intrins, post_rots, post_trans,
                                       mats, counts, task_count);
    geom_kernel<<<NBLK_PTS, 256, 0, stream>>>(mats, pcode, counts, (float4*)out);
    scan_kernel<<<1, 256, 0, stream>>>(counts, offsets, cursor, tasks, task_count);
    place_kernel<<<NBLK_PTS, 256, 0, stream>>>(pcode, cursor, entries);
    gather_kernel<<<MAXTASKS, 512, 0, stream>>>(x_feats, entries, offsets,
                                                tasks, task_count, out);
}